// Round 10
// baseline (466.486 us; speedup 1.0000x reference)
//
#include <hip/hip_runtime.h>
#include <hip/hip_bf16.h>
#include <type_traits>

// GLA attention forward: B=4,T=2048,D=2048,H=16,DK=64,DV=128,LR=16
// Inputs/outputs f32; bf16 internally. Chunked GLA (chunk=64) +
// 256^2 GEMM, 32x32x16 MFMA, 4-phase/K-tile with one-phase-ahead
// register prefetch of LDS fragments (reads overlap prior phase's MFMA).

using bf16x8 = __attribute__((ext_vector_type(8))) short;
using f32x4  = __attribute__((ext_vector_type(4))) float;
using f32x16 = __attribute__((ext_vector_type(16))) float;

static __device__ __forceinline__ float bf2f(ushort u) {
  union { unsigned int i; float f; } v;
  v.i = ((unsigned int)u) << 16;
  return v.f;
}
static __device__ __forceinline__ ushort f2bf(float f) {
  __hip_bfloat16 h = __float2bfloat16(f);
  return *reinterpret_cast<ushort*>(&h);
}
static __device__ __forceinline__ unsigned int pack2(float lo, float hi) {
  return (unsigned int)f2bf(lo) | ((unsigned int)f2bf(hi) << 16);
}
static __device__ __forceinline__ void unpack8(uint4 v, float* f) {
  f[0] = bf2f((ushort)(v.x & 0xffff)); f[1] = bf2f((ushort)(v.x >> 16));
  f[2] = bf2f((ushort)(v.y & 0xffff)); f[3] = bf2f((ushort)(v.y >> 16));
  f[4] = bf2f((ushort)(v.z & 0xffff)); f[5] = bf2f((ushort)(v.z >> 16));
  f[6] = bf2f((ushort)(v.w & 0xffff)); f[7] = bf2f((ushort)(v.w >> 16));
}

#define GLDS16(g, l) __builtin_amdgcn_global_load_lds( \
    (const __attribute__((address_space(1))) unsigned int*)(g), \
    (__attribute__((address_space(3))) unsigned int*)(l), 16, 0, 0)

#define SWZ3(row) ((((row) & 1) << 2) | (((row) >> 1) & 3))

// segmented in-place cumsum over gc[64][65] columns, 256 threads
#define GC_CUMSUM(gc, th)                                              \
  {                                                                    \
    const int k_ = (th) & 63, seg_ = (th) >> 6;                        \
    float s_ = 0.f;                                                    \
    _Pragma("unroll")                                                  \
    for (int i_ = 0; i_ < 16; ++i_) {                                  \
      s_ += gc[seg_ * 16 + i_][k_];                                    \
      gc[seg_ * 16 + i_][k_] = s_;                                     \
    }                                                                  \
    __syncthreads();                                                   \
    float t0_ = gc[15][k_], t1_ = gc[31][k_], t2_ = gc[47][k_];        \
    __syncthreads();                                                   \
    float off_ = (seg_ > 0 ? t0_ : 0.f) + (seg_ > 1 ? t1_ : 0.f) +     \
                 (seg_ > 2 ? t2_ : 0.f);                               \
    if (seg_) {                                                        \
      _Pragma("unroll")                                                \
      for (int i_ = 0; i_ < 16; ++i_) gc[seg_ * 16 + i_][k_] += off_;  \
    }                                                                  \
    __syncthreads();                                                   \
  }

// ---------------- fused 4-weight transpose f32 -> bf16 [6144][2048] ----------------
__global__ __launch_bounds__(256) void transpose_w4(
    const float* __restrict__ Wq, const float* __restrict__ Wk,
    const float* __restrict__ Wv, const float* __restrict__ Wg,
    ushort* __restrict__ WT) {
  const int bx = blockIdx.x;
  const float* src; int srcC, colbase, outrow0;
  if (bx < 16)      { src = Wq; srcC = 1024; colbase = bx * 64;        outrow0 = 0; }
  else if (bx < 32) { src = Wk; srcC = 1024; colbase = (bx - 16) * 64; outrow0 = 1024; }
  else if (bx < 64) { src = Wv; srcC = 2048; colbase = (bx - 32) * 64; outrow0 = 2048; }
  else              { src = Wg; srcC = 2048; colbase = (bx - 64) * 64; outrow0 = 4096; }
  __shared__ float tile[64][65];
  const int t = threadIdx.x;
  const int tr = blockIdx.y * 64;
  const int lr = t >> 2;
  const int lc = (t & 3) * 16;
  const float* ip = src + (long)(tr + lr) * srcC + colbase + lc;
#pragma unroll
  for (int j = 0; j < 4; ++j)
    *(float4*)(&tile[lr][lc + j * 4]) = *(const float4*)(ip + j * 4);
  __syncthreads();
  const int c = t >> 2;
  const int r0 = (t & 3) * 16;
  ushort tmp[16];
#pragma unroll
  for (int j = 0; j < 16; ++j) tmp[j] = f2bf(tile[r0 + j][c]);
  ushort* op = WT + (long)(outrow0 + colbase + c) * 2048 + tr + r0;
  *(uint4*)(op)     = *(uint4*)(tmp);
  *(uint4*)(op + 8) = *(uint4*)(tmp + 8);
}

// ---------------- transpose f32 in[R][C] -> bf16 out[C][R] (Wo) ----------------
__global__ __launch_bounds__(256) void transpose_f32_bf16(
    const float* __restrict__ in, ushort* __restrict__ out, int R, int C) {
  __shared__ float tile[64][65];
  const int t = threadIdx.x;
  const int tc = blockIdx.x * 64;
  const int tr = blockIdx.y * 64;
  const int lr = t >> 2;
  const int lc = (t & 3) * 16;
  const float* ip = in + (long)(tr + lr) * C + tc + lc;
#pragma unroll
  for (int j = 0; j < 4; ++j)
    *(float4*)(&tile[lr][lc + j * 4]) = *(const float4*)(ip + j * 4);
  __syncthreads();
  const int c = t >> 2;
  const int r0 = (t & 3) * 16;
  ushort tmp[16];
#pragma unroll
  for (int j = 0; j < 16; ++j) tmp[j] = f2bf(tile[r0 + j][c]);
  ushort* op = out + (long)(tc + c) * R + tr + r0;
  *(uint4*)(op)     = *(uint4*)(tmp);
  *(uint4*)(op + 8) = *(uint4*)(tmp + 8);
}

// ---------------- 256x256 GEMM (32x32x16 MFMA), prefetched 4-phase ----------------
// Phase p: lgkmcnt(0) [frags read at p-1 ready] -> issue phase-p+1 ds_reads + stage
// -> MFMA. Phase 3: vmcnt(6) then prefetch next-K-tile frags from other buffer.
// Stage-write vs read ordering: every stage targets a region whose reads COMPLETED
// (pinned by consuming lgkmcnt(0)) >=1 barrier earlier. Boundary vmcnt(6): 6 newest
// outstanding = kt+2's stages -> kt+1's buffer fully staged before its prefetch.
template <typename OT>
__global__ __launch_bounds__(512, 1) void gemm_bt8(
    const ushort* __restrict__ A, const ushort* __restrict__ BT,
    OT* __restrict__ C, int M, int N, int K) {
  __shared__ ushort sA[2 * 16384];
  __shared__ ushort sB[2 * 16384];
  const int t = threadIdx.x;
  const int nbx = N >> 8;
  const int cpx = gridDim.x >> 3;
  const int wg = ((int)blockIdx.x & 7) * cpx + ((int)blockIdx.x >> 3);
  const int brow = (wg / nbx) * 256;
  const int bcol = (wg % nbx) * 256;

  const int w = t >> 6, l = t & 63;
  const int wm = w >> 2, wn = w & 3;
  const int l31 = l & 31, l5 = l >> 5;
  const int NT = K >> 6;

  const int srow = t >> 3;
  const int cswz = ((t & 7) ^ SWZ3(srow)) * 8;
  const ushort* Abase = A + (size_t)(brow + srow) * K + cswz;
  const ushort* Bbase = BT + (size_t)(bcol + srow) * K + cswz;
  const int t8 = t * 8;

  auto stageA = [&](int bb, int hh, int jt) {
    const ushort* s = Abase + (size_t)(hh * 128) * K + jt * 64;
    ushort* d = sA + bb * 16384 + hh * 8192 + t8;
    GLDS16(s, d);
    GLDS16(s + (size_t)64 * K, d + 4096);
  };
  auto stageB = [&](int bb, int hh, int jt) {
    const ushort* s = Bbase + (size_t)(hh * 128) * K + jt * 64;
    ushort* d = sB + bb * 16384 + hh * 8192 + t8;
    GLDS16(s, d);
    GLDS16(s + (size_t)64 * K, d + 4096);
  };

  const int swz = SWZ3(l31 & 7);
  const int aRow = (wm * 32 + l31) * 64;
  const int bRow = (wn * 32 + l31) * 64;
#define KSL(ks) ((((ks) * 2 + l5) ^ swz) * 8)

  f32x16 acc[4][2];
#pragma unroll
  for (int m = 0; m < 4; ++m)
#pragma unroll
    for (int n = 0; n < 2; ++n)
#pragma unroll
      for (int r = 0; r < 16; ++r) acc[m][n][r] = 0.f;

  bf16x8 aF0[2][4], aF1[2][4], bF0[4], bF1[4];

  // prologue: stage kt0 (4 halves) + kt1 (3 halves); vmcnt(6) drains kt0
  stageA(0, 0, 0); stageB(0, 0, 0); stageB(0, 1, 0); stageA(0, 1, 0);
  stageA(1, 0, 1); stageB(1, 0, 1); stageB(1, 1, 1);
  asm volatile("s_waitcnt vmcnt(6)" ::: "memory");
  __builtin_amdgcn_s_barrier();
  // prologue reads: kt0 phase-0 fragments (Ah0, Bh0)
#pragma unroll
  for (int mf = 0; mf < 2; ++mf)
#pragma unroll
    for (int ks = 0; ks < 4; ++ks)
      aF0[mf][ks] = *(const bf16x8*)(sA + mf * 4096 + aRow + KSL(ks));
#pragma unroll
  for (int ks = 0; ks < 4; ++ks)
    bF0[ks] = *(const bf16x8*)(sB + bRow + KSL(ks));

  for (int kt = 0; kt < NT; ++kt) {
    const int bb = kt & 1;
    const int off = bb * 16384;
    const int nxt = off ^ 16384;

    // ---- phase 0: MFMA aF0 x bF0; prefetch bF1; stage kt+1.Ah1 ----
    asm volatile("s_waitcnt lgkmcnt(0)" ::: "memory");
    __builtin_amdgcn_sched_barrier(0);
#pragma unroll
    for (int ks = 0; ks < 4; ++ks)
      bF1[ks] = *(const bf16x8*)(sB + off + 8192 + bRow + KSL(ks));
    if (kt + 1 < NT) stageA(bb ^ 1, 1, kt + 1);
    __builtin_amdgcn_sched_barrier(0);
    __builtin_amdgcn_s_setprio(1);
#pragma unroll
    for (int mf = 0; mf < 2; ++mf)
#pragma unroll
      for (int ks = 0; ks < 4; ++ks)
        acc[mf][0] = __builtin_amdgcn_mfma_f32_32x32x16_bf16(aF0[mf][ks], bF0[ks], acc[mf][0], 0, 0, 0);
    __builtin_amdgcn_s_setprio(0);
    __builtin_amdgcn_s_barrier();

    // ---- phase 1: MFMA aF0 x bF1; prefetch aF1 (Ah1); stage kt+2.Ah0 ----
    asm volatile("s_waitcnt lgkmcnt(0)" ::: "memory");
    __builtin_amdgcn_sched_barrier(0);
#pragma unroll
    for (int mf = 0; mf < 2; ++mf)
#pragma unroll
      for (int ks = 0; ks < 4; ++ks)
        aF1[mf][ks] = *(const bf16x8*)(sA + off + 8192 + mf * 4096 + aRow + KSL(ks));
    if (kt + 2 < NT) stageA(bb, 0, kt + 2);
    __builtin_amdgcn_sched_barrier(0);
    __builtin_amdgcn_s_setprio(1);
#pragma unroll
    for (int mf = 0; mf < 2; ++mf)
#pragma unroll
      for (int ks = 0; ks < 4; ++ks)
        acc[mf][1] = __builtin_amdgcn_mfma_f32_32x32x16_bf16(aF0[mf][ks], bF1[ks], acc[mf][1], 0, 0, 0);
    __builtin_amdgcn_s_setprio(0);
    __builtin_amdgcn_s_barrier();

    // ---- phase 2: MFMA aF1 x bF0; no reads; stage kt+2.Bh0 ----
    asm volatile("s_waitcnt lgkmcnt(0)" ::: "memory");
    __builtin_amdgcn_sched_barrier(0);
    if (kt + 2 < NT) stageB(bb, 0, kt + 2);
    __builtin_amdgcn_sched_barrier(0);
    __builtin_amdgcn_s_setprio(1);
#pragma unroll
    for (int mf = 0; mf < 2; ++mf)
#pragma unroll
      for (int ks = 0; ks < 4; ++ks)
        acc[2 + mf][0] = __builtin_amdgcn_mfma_f32_32x32x16_bf16(aF1[mf][ks], bF0[ks], acc[2 + mf][0], 0, 0, 0);
    __builtin_amdgcn_s_setprio(0);
    __builtin_amdgcn_s_barrier();

    // ---- phase 3: MFMA aF1 x bF1; stage kt+2.Bh1; vmcnt; prefetch next-kt aF0,bF0 ----
    if (kt + 2 < NT) stageB(bb, 1, kt + 2);
    if (kt < NT - 2)       asm volatile("s_waitcnt vmcnt(6)" ::: "memory");
    else if (kt == NT - 2) asm volatile("s_waitcnt vmcnt(0)" ::: "memory");
    if (kt + 1 < NT) {
#pragma unroll
      for (int mf = 0; mf < 2; ++mf)
#pragma unroll
        for (int ks = 0; ks < 4; ++ks)
          aF0[mf][ks] = *(const bf16x8*)(sA + nxt + mf * 4096 + aRow + KSL(ks));
#pragma unroll
      for (int ks = 0; ks < 4; ++ks)
        bF0[ks] = *(const bf16x8*)(sB + nxt + bRow + KSL(ks));
    }
    __builtin_amdgcn_sched_barrier(0);
    __builtin_amdgcn_s_setprio(1);
#pragma unroll
    for (int mf = 0; mf < 2; ++mf)
#pragma unroll
      for (int ks = 0; ks < 4; ++ks)
        acc[2 + mf][1] = __builtin_amdgcn_mfma_f32_32x32x16_bf16(aF1[mf][ks], bF1[ks], acc[2 + mf][1], 0, 0, 0);
    __builtin_amdgcn_s_setprio(0);
    __builtin_amdgcn_s_barrier();
  }
#undef KSL

  // epilogue: 32x32 C/D layout col=lane&31, row=(reg&3)+8*(reg>>2)+4*(lane>>5)
#pragma unroll
  for (int mf = 0; mf < 4; ++mf)
#pragma unroll
    for (int nf = 0; nf < 2; ++nf) {
      long col = bcol + nf * 128 + wn * 32 + l31;
      long rbase = brow + mf * 64 + wm * 32 + 4 * l5;
#pragma unroll
      for (int r = 0; r < 16; ++r) {
        long row = rbase + (r & 3) + 8 * (r >> 2);
        if constexpr (std::is_same_v<OT, ushort>) C[row * N + col] = f2bf(acc[mf][nf][r]);
        else                                      C[row * N + col] = acc[mf][nf][r];
      }
    }
}

// ---------------- gate path: 8 rows/block; also emits xb = bf16(x) ----------------
__global__ __launch_bounds__(256) void gate_kernel(
    const float* __restrict__ x, const float* __restrict__ Wgk1,
    const float* __restrict__ Wgk2, const float* __restrict__ bgk2,
    ushort* __restrict__ xb, ushort* __restrict__ gbuf) {
  const long m0 = (long)blockIdx.x * 8;
  const int t = threadIdx.x;
  __shared__ float sx[8][2048];
  __shared__ float red[16][8][16];
  __shared__ float z1[8][16];
#pragma unroll
  for (int u = 0; u < 8; ++u) {
    int idx = (u * 256 + t) * 8;
    int r = idx >> 11, cc = idx & 2047;
    const float* xp = x + (m0 + r) * 2048 + cc;
    float4 a = *(const float4*)xp;
    float4 b = *(const float4*)(xp + 4);
    *(float4*)(&sx[r][cc])     = a;
    *(float4*)(&sx[r][cc + 4]) = b;
    uint4 o;
    o.x = pack2(a.x, a.y); o.y = pack2(a.z, a.w);
    o.z = pack2(b.x, b.y); o.w = pack2(b.z, b.w);
    *(uint4*)(xb + (m0 + r) * 2048 + cc) = o;
  }
  __syncthreads();
  const int j = t & 15, dg = t >> 4;
  float a8[8] = {0.f, 0.f, 0.f, 0.f, 0.f, 0.f, 0.f, 0.f};
  const float* wp = Wgk1 + (dg * 128) * 16 + j;
  for (int dc = 0; dc < 128; dc += 4) {
    float w0 = wp[(dc + 0) * 16], w1 = wp[(dc + 1) * 16];
    float w2 = wp[(dc + 2) * 16], w3 = wp[(dc + 3) * 16];
    const int dd = dg * 128 + dc;
#pragma unroll
    for (int r = 0; r < 8; ++r) {
      float4 xv = *(const float4*)(&sx[r][dd]);
      a8[r] += xv.x * w0 + xv.y * w1 + xv.z * w2 + xv.w * w3;
    }
  }
#pragma unroll
  for (int r = 0; r < 8; ++r) red[dg][r][j] = a8[r];
  __syncthreads();
  if (t < 128) {
    int r = t >> 4, jj = t & 15;
    float s = 0.f;
#pragma unroll
    for (int g = 0; g < 16; ++g) s += red[g][r][jj];
    z1[r][jj] = s;
  }
  __syncthreads();
#pragma unroll
  for (int q = 0; q < 4; ++q) {
    int n = q * 256 + t;
    float w2v[16];
#pragma unroll
    for (int l2 = 0; l2 < 16; ++l2) w2v[l2] = Wgk2[l2 * 1024 + n];
    float bb = bgk2[n];
#pragma unroll
    for (int r = 0; r < 8; ++r) {
      float a = bb;
#pragma unroll
      for (int l2 = 0; l2 < 16; ++l2) a += z1[r][l2] * w2v[l2];
      float ls = fminf(a, 0.f) - log1pf(__expf(-fabsf(a)));
      gbuf[(m0 + r) * 1024 + n] = f2bf(ls * 0.0625f);
    }
  }
}

// ---------------- Phase A: per-chunk contribution -> bf16 S^T [128dv][64k] ----------------
__global__ __launch_bounds__(256) void chunk_contrib_kernel(
    const ushort* __restrict__ qkvg, const ushort* __restrict__ gbuf,
    ushort* __restrict__ STbuf, float* __restrict__ EGtot) {
  const int blk = blockIdx.x;           // 2048 = bh*32 + c
  const int bh = blk >> 5, c = blk & 31;
  const int b = bh >> 4, h = bh & 15;
  const long row0 = (long)b * 2048 + c * 64;
  const int th = threadIdx.x;

  __shared__ float  gc[64][65];
  __shared__ ushort khT[64][72];
  __shared__ ushort vT[128][72];

  {
    const int t = th >> 2;
    const int k0 = (th & 3) * 16;
    const ushort* gp = gbuf + (row0 + t) * 1024 + h * 64 + k0;
    uint4 a = *(const uint4*)gp;
    uint4 b4 = *(const uint4*)(gp + 8);
    float f[8];
    unpack8(a, f);
#pragma unroll
    for (int j = 0; j < 8; ++j) gc[t][k0 + j] = f[j];
    unpack8(b4, f);
#pragma unroll
    for (int j = 0; j < 8; ++j) gc[t][k0 + 8 + j] = f[j];
  }
  __syncthreads();
  GC_CUMSUM(gc, th)
  if (th < 64) EGtot[(long)blk * 64 + th] = __expf(gc[63][th]);

  {
    const int s = th & 63, kq = th >> 6;
    const ushort* kp = qkvg + (row0 + s) * 6144 + 1024 + h * 64 + kq * 16;
    uint4 a = *(const uint4*)kp;
    uint4 b4 = *(const uint4*)(kp + 8);
    float f[16];
    unpack8(a, f); unpack8(b4, f + 8);
#pragma unroll
    for (int j = 0; j < 16; ++j) {
      int k = kq * 16 + j;
      khT[k][s] = f2bf(f[j] * __expf(gc[63][k] - gc[s][k]));
    }
    const ushort* vp = qkvg + (row0 + s) * 6144 + 2048 + h * 128 + kq * 32;
#pragma unroll
    for (int u = 0; u < 4; ++u) {
      uint4 vv = *(const uint4*)(vp + u * 8);
      const ushort* pv = (const ushort*)&vv;
#pragma unroll
      for (int j = 0; j < 8; ++j) vT[kq * 32 + u * 8 + j][s] = pv[j];
    }
  }
  __syncthreads();

  const int w = th >> 6, l = th & 63;
  const int lr = l & 15, kq8 = (l >> 4) * 8;
  f32x4 acc[4][2];
#pragma unroll
  for (int m = 0; m < 4; ++m)
#pragma unroll
    for (int n = 0; n < 2; ++n) acc[m][n] = (f32x4){0.f, 0.f, 0.f, 0.f};
#pragma unroll
  for (int ks = 0; ks < 64; ks += 32) {
#pragma unroll
    for (int m = 0; m < 4; ++m) {
      bf16x8 af = *(const bf16x8*)(&khT[m * 16 + lr][ks + kq8]);
#pragma unroll
      for (int n = 0; n < 2; ++n) {
        bf16x8 bv = *(const bf16x8*)(&vT[w * 32 + n * 16 + lr][ks + kq8]);
        acc[m][n] = __builtin_amdgcn_mfma_f32_16x16x32_bf16(af, bv, acc[m][n], 0, 0, 0);
      }
    }
  }
  ushort* Cc = STbuf + (long)blk * 8192;
  const int rq = (l >> 4) * 4;
#pragma unroll
  for (int m = 0; m < 4; ++m)
#pragma unroll
    for (int n = 0; n < 2; ++n) {
      int dv = w * 32 + n * 16 + lr;
      ushort tmp[4];
#pragma unroll
      for (int r = 0; r < 4; ++r) tmp[r] = f2bf(acc[m][n][r]);
      *(uint2*)(Cc + dv * 64 + m * 16 + rq) = *(uint2*)tmp;
    }
}

// ---------------- Phase B: chunk scan on bf16 S^T, f32 running state ----------------
__global__ __launch_bounds__(256) void chunk_scan_kernel(
    ushort* __restrict__ STbuf, const float* __restrict__ EGtot) {
  const int blk = blockIdx.x;      // 256 = bh*4 + qd
  const int bh = blk >> 2, qd = blk & 3;
  const int th = threadIdx.x;
  const int dv = qd * 32 + (th >> 3);
  const int k0 = (th & 7) * 8;
  ushort* base = STbuf + (long)bh * 32 * 8192 + dv * 64 + k0;
  const float* eg = EGtot + (long)bh * 32 * 64 + k0;
  float S[8];
#pragma unroll
  for (int i = 0; i < 8; ++i) S[i] = 0.f;
  uint4 cv = *(const uint4*)base;
  float4 e0 = *(const float4*)(eg);
  float4 e1 = *(const float4*)(eg + 4);
  for (int c = 0; c < 32; ++c) {
    ushort* cur = base;
    base += 8192; eg += 64;
    uint4 nv = cv; float4 n0 = e0, n1 = e1;
    if (c < 31) {
      nv = *(const uint4*)base;
      n0 = *(const float4*)(eg);
      n1 = *(const float4*)(eg + 4);
    }
    float cf[8];
    unpack8(cv, cf);
    float ee[8] = {e0.x, e0.y, e0.z, e0.w, e1.x, e1.y, e1.z, e1.w};
    ushort so[8];
#pragma unroll
    for (int i = 0; i < 8; ++i) {
      so[i] = f2bf(S[i]);
      S[i] = S[i] * ee[i] + cf[i];
    }
    *(uint4*)cur = *(uint4*)so;
    cv = nv; e0 = n0; e1 = n1;
  }
}

// ---------------- Phase C: chunk output + fused RMSNorm*swish gate ----------------
__global__ __launch_bounds__(256) void chunk_output_kernel(
    const ushort* __restrict__ qkvg, const ushort* __restrict__ gbuf,
    const ushort* __restrict__ STbuf, const float* __restrict__ norm_w,
    ushort* __restrict__ oo) {
  const int blk = blockIdx.x;
  const int bh = blk >> 5, c = blk & 31;
  const int b = bh >> 4, h = bh & 15;
  const long row0 = (long)b * 2048 + c * 64;
  const int th = threadIdx.x;

  __shared__ __align__(16) char pool[71936];
  float  (*gc)[65]  = (float(*)[65])(pool);
  ushort (*qg)[72]  = (ushort(*)[72])(pool + 16640);
  ushort (*kg)[72]  = (ushort(*)[72])(pool + 25856);
  ushort (*vT)[72]  = (ushort(*)[72])(pool + 35072);
  ushort (*STs)[72] = (ushort(*)[72])(pool + 53504);
  ushort (*P)[72]   = (ushort(*)[72])(pool);   // alias over gc (dead after exp-apply)

  {
    const int t = th >> 2;
    const int k0 = (th & 3) * 16;
    const ushort* gp = gbuf + (row0 + t) * 1024 + h * 64 + k0;
    uint4 a = *(const uint4*)gp;
    uint4 b4 = *(const uint4*)(gp + 8);
    float f[8];
    unpack8(a, f);
#pragma unroll
    for (int j = 0; j < 8; ++j) gc[t][k0 + j] = f[j];
    unpack8(b4, f);
#pragma unroll
    for (int j = 0; j < 8; ++j) gc[t][k0 + 8 + j] = f[j];

    const ushort* qp = qkvg + (row0 + t) * 6144 + h * 64 + k0;
    *(uint4*)(&qg[t][k0])     = *(const uint4*)qp;
    *(uint4*)(&qg[t][k0 + 8]) = *(const uint4*)(qp + 8);
    const ushort* kp = qp + 1024;
    *(uint4*)(&kg[t][k0])     = *(const uint4*)kp;
    *(uint4*)(&kg[t][k0 + 8]) = *(const uint4*)(kp + 8);
  }
  {
    const int s = th & 63, kq = th >> 6;
    const ushort* vp = qkvg + (row0 + s) * 6144 + 2048 + h * 128 + kq * 32;
#pragma unroll
    for (int u = 0; u < 4; ++u) {
      uint4 vv = *(const uint4*)(vp + u * 8);
      const ushort* pv = (const ushort*)&vv;
#pragma unroll
      for (int j = 0; j < 8; ++j) vT[kq * 32 + u * 8 + j][s] = pv[j];
    }
  }
  {
    const int row = th >> 1;
    const int col0 = (th & 1) * 32;
    const ushort* sp = STbuf + (long)blk * 8192 + row * 64 + col0;
#pragma unroll
    for (int u = 0; u < 4; ++u)
      *(uint4*)(&STs[row][col0 + u * 8]) = *(const uint4*)(sp + u * 8);
  }
  __syncthreads();
  GC_CUMSUM(gc, th)
  {
    const int t = th & 63, kb = (th >> 6) * 16;
#pragma unroll
    for (int u = 0; u < 2; ++u) {
      uint4 qv = *(const uint4*)(&qg[t][kb + u * 8]);
      uint4 kv = *(const uint4*)(&kg[t][kb + u * 8]);
      float qf[8], kf[8];
      unpack8(qv, qf); unpack8(kv, kf);
      ushort qo[8], ko[8];
#pragma unroll
      for (int j = 0; j < 8; ++j) {
        float g = gc[t][kb + u * 8 + j];
        qo[j] = f2bf(qf[j] * __expf(g) * 0.125f);
        ko[j] = f2bf(kf[j] * __expf(-g));
      }
      *(uint4*)(&qg[t][kb + u * 8]) = *(uint4*)qo;
      *(uint4*)(&kg[t][kb + u * 8]) = *(uint4*)ko;
    }
  }
  __syncthreads();

  const int w = th >> 6, l = th & 63;
  const int lr = l & 15, kq8 = (l >> 4) * 8;
  const int rq = (l >> 4) * 4;

  f32x4 acc1[4];
#pragma unroll
  for (int n = 0; n < 4; ++n) acc1[n] = (f32x4){0.f, 0.f, 0.f, 0.f};
#pragma unroll
  for (int kk = 0; kk < 64; kk += 32) {
    bf16x8 af = *(const bf16x8*)(&qg[w * 16 + lr][kk + kq8]);
#pragma unroll
    for (int n = 0; n < 4; ++n) {
      bf16x8 bv = *(const bf16x8*)(&kg[n * 16 + lr][kk + kq8]);
      acc1[n] = __builtin_amdgcn_mfma_f32_16x16x32_bf16(af, bv, acc1[n], 0, 0, 0);
    }
  }
#pragma unroll
  for (int n = 0; n < 4; ++n) {
    int s = n * 16 + lr;
#pragma unroll
    for (int r = 0; r < 4; ++r) {
      int t = w * 16 + rq + r;
      P[t][s] = f2bf(s <= t ? acc1[n][r] : 0.f);
    }
  }
  __syncthreads();

  f32x4 acc2[8];
#pragma unroll
  for (int n = 0; n < 8; ++n) acc2[n] = (f32x4){0.f, 0.f, 0.f, 0.f};
#pragma unroll
  for (int ks = 0; ks < 64; ks += 32) {
    bf16x8 af = *(const bf16x8*)(&P[w * 16 + lr][ks + kq8]);
#pragma unroll
    for (int n = 0; n < 8; ++n) {
      bf16x8 bv = *(const bf16x8*)(&vT[n * 16 + lr][ks + kq8]);
      acc2[n] = __builtin_amdgcn_mfma_f32_16x16x32_bf16(af, bv, acc2[n], 0, 0, 0);
    }
  }
#pragma unroll
  for (int kk = 0; kk < 64; kk += 32) {
    bf16x8 af = *(const bf16x8*)(&qg[w * 16 + lr][kk + kq8]);
#pragma unroll
    for (int n = 0; n < 8; ++n) {
      bf16x8 bv = *(const bf16x8*)(&STs[n * 16 + lr][kk + kq8]);
      acc2[n] = __builtin_amdgcn_mfma_f32_16x16x32_bf16(af, bv, acc2[n], 0, 0, 0);
    }
  }

  float gv[8][4];
#pragma unroll
  for (int n = 0; n < 8; ++n) {
    int dv = n * 16 + lr;
#pragma unroll
    for (int r = 0; r < 4; ++r)
      gv[n][r] = bf2f(qkvg[(row0 + w * 16 + rq + r) * 6144 + 4096 + h * 128 + dv]);
  }

  float sumsq[4] = {0.f, 0.f, 0.f, 0.f};
#pragma unroll
  for (int n = 0; n < 8; ++n)
#pragma unroll
    for (int r = 0; r < 4; ++r) sumsq[r] += acc2[n][r] * acc2[n][r];
#pragma unroll
  for (int d = 1; d < 16; d <<= 1)
#pragma unroll
    for (int r = 0; r < 4; ++r) sumsq[r] += __shfl_xor(sumsq[r], d);
  float inv[4];
#pragma unroll
  for (int r = 0; r < 4; ++r) inv[r] = rsqrtf(sumsq[r] * (1.f / 128.f) + 1e-5f);

#pragma unroll
  for (int n = 0; n < 8; ++n) {
    int dv = n * 16 + lr;
    float nw = norm_w[dv];
#pragma unroll
    for (int r = 0; r < 4; ++r) {
      float g = gv[n][r];
      float sw = g / (1.f + __expf(-g));
      oo[(row0 + w * 16 + rq + r) * 2048 + h * 128 + dv] =
          f2bf(acc2[n][r] * inv[r] * nw * sw);
    }
  }
}

extern "C" void kernel_launch(void* const* d_in, const int* in_sizes, int n_in,
                              void* d_out, int out_size, void* d_ws, size_t ws_size,
                              hipStream_t stream) {
  const float* x      = (const float*)d_in[0];
  const float* Wq     = (const float*)d_in[1];
  const float* Wk     = (const float*)d_in[2];
  const float* Wv     = (const float*)d_in[3];
  const float* Wg     = (const float*)d_in[4];
  const float* Wgk1   = (const float*)d_in[5];
  const float* Wgk2   = (const float*)d_in[6];
  const float* bgk2   = (const float*)d_in[7];
  const float* norm_w = (const float*)d_in[8];
  const float* Wo     = (const float*)d_in[9];
  float* out = (float*)d_out;

  char* ws = (char*)d_ws;
  ushort* WT    = (ushort*)(ws);                       // [6144][2048] bf16  25,165,824
  ushort* WoT   = (ushort*)(ws + 25165824);            // [2048][2048] bf16   8,388,608
  ushort* qkvg  = (ushort*)(ws + 33554432);            // [8192][6144] bf16 100,663,296
  ushort* gbuf  = (ushort*)(ws + 134217728);           // [8192][1024] bf16  16,777,216
  ushort* STbuf = (ushort*)(ws + 150994944);           // [2048][128][64] bf16 33,554,432
  ushort* xb    = (ushort*)(ws + 150994944);           // overlay: dead before contrib
  float*  EGtot = (float*)(ws + 184549376);            // [2048][64] f32        524,288
  ushort* oo    = (ushort*)(ws + 185073664);           // [8192][2048] bf16  33,554,432

  dim3 blk(256);
  gate_kernel<<<dim3(1024), blk, 0, stream>>>(x, Wgk1, Wgk2, bgk2, xb, gbuf);
  transpose_w4<<<dim3(96, 32), blk, 0, stream>>>(Wq, Wk, Wv, Wg, WT);
  transpose_f32_bf16<<<dim3(32, 32), blk, 0, stream>>>(Wo, WoT, 2048, 2048);

  gemm_bt8<ushort><<<dim3(768), dim3(512), 0, stream>>>(xb, WT, qkvg, 8192, 6144, 2048);

  chunk_contrib_kernel<<<dim3(2048), blk, 0, stream>>>(qkvg, gbuf, STbuf, EGtot);
  chunk_scan_kernel<<<dim3(256), blk, 0, stream>>>(STbuf, EGtot);
  chunk_output_kernel<<<dim3(2048), blk, 0, stream>>>(qkvg, gbuf, STbuf, norm_w, oo);

  gemm_bt8<float><<<dim3(256), dim3(512), 0, stream>>>(oo, WoT, out, 8192, 2048, 2048);
}

// Round 11
// 454.734 us; speedup vs baseline: 1.0258x; 1.0258x over previous
//
#include <hip/hip_runtime.h>
#include <hip/hip_bf16.h>
#include <type_traits>

// GLA attention forward: B=4,T=2048,D=2048,H=16,DK=64,DV=128,LR=16
// Inputs/outputs f32; bf16 internally. Chunked GLA (chunk=64) +
// 256^2 4-phase GEMM with 32x32x16 MFMA (round-8 schedule, best measured).

using bf16x8 = __attribute__((ext_vector_type(8))) short;
using f32x4  = __attribute__((ext_vector_type(4))) float;
using f32x16 = __attribute__((ext_vector_type(16))) float;

static __device__ __forceinline__ float bf2f(ushort u) {
  union { unsigned int i; float f; } v;
  v.i = ((unsigned int)u) << 16;
  return v.f;
}
static __device__ __forceinline__ ushort f2bf(float f) {
  __hip_bfloat16 h = __float2bfloat16(f);
  return *reinterpret_cast<ushort*>(&h);
}
static __device__ __forceinline__ unsigned int pack2(float lo, float hi) {
  return (unsigned int)f2bf(lo) | ((unsigned int)f2bf(hi) << 16);
}
static __device__ __forceinline__ void unpack8(uint4 v, float* f) {
  f[0] = bf2f((ushort)(v.x & 0xffff)); f[1] = bf2f((ushort)(v.x >> 16));
  f[2] = bf2f((ushort)(v.y & 0xffff)); f[3] = bf2f((ushort)(v.y >> 16));
  f[4] = bf2f((ushort)(v.z & 0xffff)); f[5] = bf2f((ushort)(v.z >> 16));
  f[6] = bf2f((ushort)(v.w & 0xffff)); f[7] = bf2f((ushort)(v.w >> 16));
}

#define GLDS16(g, l) __builtin_amdgcn_global_load_lds( \
    (const __attribute__((address_space(1))) unsigned int*)(g), \
    (__attribute__((address_space(3))) unsigned int*)(l), 16, 0, 0)

#define SWZ3(row) ((((row) & 1) << 2) | (((row) >> 1) & 3))

// segmented in-place cumsum over gc[64][65] columns, 256 threads
#define GC_CUMSUM(gc, th)                                              \
  {                                                                    \
    const int k_ = (th) & 63, seg_ = (th) >> 6;                        \
    float s_ = 0.f;                                                    \
    _Pragma("unroll")                                                  \
    for (int i_ = 0; i_ < 16; ++i_) {                                  \
      s_ += gc[seg_ * 16 + i_][k_];                                    \
      gc[seg_ * 16 + i_][k_] = s_;                                     \
    }                                                                  \
    __syncthreads();                                                   \
    float t0_ = gc[15][k_], t1_ = gc[31][k_], t2_ = gc[47][k_];        \
    __syncthreads();                                                   \
    float off_ = (seg_ > 0 ? t0_ : 0.f) + (seg_ > 1 ? t1_ : 0.f) +     \
                 (seg_ > 2 ? t2_ : 0.f);                               \
    if (seg_) {                                                        \
      _Pragma("unroll")                                                \
      for (int i_ = 0; i_ < 16; ++i_) gc[seg_ * 16 + i_][k_] += off_;  \
    }                                                                  \
    __syncthreads();                                                   \
  }

// ---------------- fused 5-weight transpose f32 -> bf16 ----------------
__global__ __launch_bounds__(256) void transpose_w5(
    const float* __restrict__ Wq, const float* __restrict__ Wk,
    const float* __restrict__ Wv, const float* __restrict__ Wg,
    const float* __restrict__ Wo, ushort* __restrict__ WT,
    ushort* __restrict__ WoT) {
  const int bx = blockIdx.x;   // 128 col tiles over {Wq,Wk,Wv,Wg,Wo}
  const float* src; int srcC, colbase; long outrow0; ushort* outb;
  if (bx < 16)      { src = Wq; srcC = 1024; colbase = bx * 64;        outrow0 = 0;    outb = WT; }
  else if (bx < 32) { src = Wk; srcC = 1024; colbase = (bx - 16) * 64; outrow0 = 1024; outb = WT; }
  else if (bx < 64) { src = Wv; srcC = 2048; colbase = (bx - 32) * 64; outrow0 = 2048; outb = WT; }
  else if (bx < 96) { src = Wg; srcC = 2048; colbase = (bx - 64) * 64; outrow0 = 4096; outb = WT; }
  else              { src = Wo; srcC = 2048; colbase = (bx - 96) * 64; outrow0 = 0;    outb = WoT; }
  __shared__ float tile[64][65];
  const int t = threadIdx.x;
  const int tr = blockIdx.y * 64;          // source row tile
  const int lr = t >> 2;
  const int lc = (t & 3) * 16;
  const float* ip = src + (long)(tr + lr) * srcC + colbase + lc;
#pragma unroll
  for (int j = 0; j < 4; ++j)
    *(float4*)(&tile[lr][lc + j * 4]) = *(const float4*)(ip + j * 4);
  __syncthreads();
  const int c = t >> 2;
  const int r0 = (t & 3) * 16;
  ushort tmp[16];
#pragma unroll
  for (int j = 0; j < 16; ++j) tmp[j] = f2bf(tile[r0 + j][c]);
  ushort* op = outb + (outrow0 + colbase + c) * 2048 + tr + r0;
  *(uint4*)(op)     = *(uint4*)(tmp);
  *(uint4*)(op + 8) = *(uint4*)(tmp + 8);
}

// ---------------- 256x256 GEMM (32x32x16 MFMA), round-8 4-phase schedule ----------------
template <typename OT>
__global__ __launch_bounds__(512, 2) void gemm_bt8(
    const ushort* __restrict__ A, const ushort* __restrict__ BT,
    OT* __restrict__ C, int M, int N, int K) {
  __shared__ ushort sA[2 * 16384];
  __shared__ ushort sB[2 * 16384];
  const int t = threadIdx.x;
  const int nbx = N >> 8;
  const int cpx = gridDim.x >> 3;
  const int wg = ((int)blockIdx.x & 7) * cpx + ((int)blockIdx.x >> 3);
  const int brow = (wg / nbx) * 256;
  const int bcol = (wg % nbx) * 256;

  const int w = t >> 6, l = t & 63;
  const int wm = w >> 2, wn = w & 3;
  const int l31 = l & 31, l5 = l >> 5;
  const int NT = K >> 6;

  const int srow = t >> 3;
  const int cswz = ((t & 7) ^ SWZ3(srow)) * 8;
  const ushort* Abase = A + (size_t)(brow + srow) * K + cswz;
  const ushort* Bbase = BT + (size_t)(bcol + srow) * K + cswz;
  const int t8 = t * 8;

  auto stageA = [&](int bb, int hh, int jt) {
    const ushort* s = Abase + (size_t)(hh * 128) * K + jt * 64;
    ushort* d = sA + bb * 16384 + hh * 8192 + t8;
    GLDS16(s, d);
    GLDS16(s + (size_t)64 * K, d + 4096);
  };
  auto stageB = [&](int bb, int hh, int jt) {
    const ushort* s = Bbase + (size_t)(hh * 128) * K + jt * 64;
    ushort* d = sB + bb * 16384 + hh * 8192 + t8;
    GLDS16(s, d);
    GLDS16(s + (size_t)64 * K, d + 4096);
  };

  const int swz = SWZ3(l31 & 7);
  const int aRow = (wm * 32 + l31) * 64;
  const int bRow = (wn * 32 + l31) * 64;
#define KSL(ks) ((((ks) * 2 + l5) ^ swz) * 8)

  f32x16 acc[4][2];
#pragma unroll
  for (int m = 0; m < 4; ++m)
#pragma unroll
    for (int n = 0; n < 2; ++n)
#pragma unroll
      for (int r = 0; r < 16; ++r) acc[m][n][r] = 0.f;

  // prologue: K-tile 0 (4 halves) -> vmcnt(4) -> K-tile 1 first 3 halves -> vmcnt(6)
  stageA(0, 0, 0); stageB(0, 0, 0); stageB(0, 1, 0); stageA(0, 1, 0);
  asm volatile("s_waitcnt vmcnt(4)" ::: "memory");
  stageA(1, 0, 1); stageB(1, 0, 1); stageB(1, 1, 1);
  asm volatile("s_waitcnt vmcnt(6)" ::: "memory");
  __builtin_amdgcn_s_barrier();

  for (int kt = 0; kt < NT; ++kt) {
    const int bb = kt & 1;
    const int aOff = bb * 16384, bOff = bb * 16384;
    bf16x8 aF[2][4], bF[2][4];

    // ---- phase 0: (mh0, nh0); stage kt+1.A.h1 ----
#pragma unroll
    for (int mf = 0; mf < 2; ++mf)
#pragma unroll
      for (int ks = 0; ks < 4; ++ks)
        aF[mf][ks] = *(const bf16x8*)(sA + aOff + mf * 4096 + aRow + KSL(ks));
#pragma unroll
    for (int ks = 0; ks < 4; ++ks)
      bF[0][ks] = *(const bf16x8*)(sB + bOff + bRow + KSL(ks));
    if (kt + 1 < NT) stageA(bb ^ 1, 1, kt + 1);
    __builtin_amdgcn_s_barrier();
    __builtin_amdgcn_s_setprio(1);
#pragma unroll
    for (int mf = 0; mf < 2; ++mf)
#pragma unroll
      for (int ks = 0; ks < 4; ++ks)
        acc[mf][0] = __builtin_amdgcn_mfma_f32_32x32x16_bf16(aF[mf][ks], bF[0][ks], acc[mf][0], 0, 0, 0);
    __builtin_amdgcn_s_setprio(0);
    __builtin_amdgcn_s_barrier();

    // ---- phase 1: (mh0, nh1); stage kt+2.A.h0 ----
#pragma unroll
    for (int ks = 0; ks < 4; ++ks)
      bF[1][ks] = *(const bf16x8*)(sB + bOff + 8192 + bRow + KSL(ks));
    if (kt + 2 < NT) stageA(bb, 0, kt + 2);
    __builtin_amdgcn_s_barrier();
    __builtin_amdgcn_s_setprio(1);
#pragma unroll
    for (int mf = 0; mf < 2; ++mf)
#pragma unroll
      for (int ks = 0; ks < 4; ++ks)
        acc[mf][1] = __builtin_amdgcn_mfma_f32_32x32x16_bf16(aF[mf][ks], bF[1][ks], acc[mf][1], 0, 0, 0);
    __builtin_amdgcn_s_setprio(0);
    __builtin_amdgcn_s_barrier();

    // ---- phase 2: (mh1, nh0); stage kt+2.B.h0 ----
#pragma unroll
    for (int mf = 0; mf < 2; ++mf)
#pragma unroll
      for (int ks = 0; ks < 4; ++ks)
        aF[mf][ks] = *(const bf16x8*)(sA + aOff + 8192 + mf * 4096 + aRow + KSL(ks));
    if (kt + 2 < NT) stageB(bb, 0, kt + 2);
    __builtin_amdgcn_s_barrier();
    __builtin_amdgcn_s_setprio(1);
#pragma unroll
    for (int mf = 0; mf < 2; ++mf)
#pragma unroll
      for (int ks = 0; ks < 4; ++ks)
        acc[2 + mf][0] = __builtin_amdgcn_mfma_f32_32x32x16_bf16(aF[mf][ks], bF[0][ks], acc[2 + mf][0], 0, 0, 0);
    __builtin_amdgcn_s_setprio(0);
    __builtin_amdgcn_s_barrier();

    // ---- phase 3: (mh1, nh1); stage kt+2.B.h1; boundary vmcnt ----
    if (kt + 2 < NT) stageB(bb, 1, kt + 2);
    __builtin_amdgcn_s_barrier();
    __builtin_amdgcn_s_setprio(1);
#pragma unroll
    for (int mf = 0; mf < 2; ++mf)
#pragma unroll
      for (int ks = 0; ks < 4; ++ks)
        acc[2 + mf][1] = __builtin_amdgcn_mfma_f32_32x32x16_bf16(aF[mf][ks], bF[1][ks], acc[2 + mf][1], 0, 0, 0);
    __builtin_amdgcn_s_setprio(0);
    if (kt < NT - 2)       asm volatile("s_waitcnt vmcnt(6)" ::: "memory");
    else if (kt == NT - 2) asm volatile("s_waitcnt vmcnt(0)" ::: "memory");
    __builtin_amdgcn_s_barrier();
  }
#undef KSL

  // epilogue: 32x32 C/D layout col=lane&31, row=(reg&3)+8*(reg>>2)+4*(lane>>5)
#pragma unroll
  for (int mf = 0; mf < 4; ++mf)
#pragma unroll
    for (int nf = 0; nf < 2; ++nf) {
      long col = bcol + nf * 128 + wn * 32 + l31;
      long rbase = brow + mf * 64 + wm * 32 + 4 * l5;
#pragma unroll
      for (int r = 0; r < 16; ++r) {
        long row = rbase + (r & 3) + 8 * (r >> 2);
        if constexpr (std::is_same_v<OT, ushort>) C[row * N + col] = f2bf(acc[mf][nf][r]);
        else                                      C[row * N + col] = acc[mf][nf][r];
      }
    }
}

// ---------------- gate path: 8 rows/block; also emits xb = bf16(x) ----------------
__global__ __launch_bounds__(256) void gate_kernel(
    const float* __restrict__ x, const float* __restrict__ Wgk1,
    const float* __restrict__ Wgk2, const float* __restrict__ bgk2,
    ushort* __restrict__ xb, ushort* __restrict__ gbuf) {
  const long m0 = (long)blockIdx.x * 8;
  const int t = threadIdx.x;
  __shared__ float sx[8][2048];
  __shared__ float red[16][8][16];
  __shared__ float z1[8][16];
#pragma unroll
  for (int u = 0; u < 8; ++u) {
    int idx = (u * 256 + t) * 8;
    int r = idx >> 11, cc = idx & 2047;
    const float* xp = x + (m0 + r) * 2048 + cc;
    float4 a = *(const float4*)xp;
    float4 b = *(const float4*)(xp + 4);
    *(float4*)(&sx[r][cc])     = a;
    *(float4*)(&sx[r][cc + 4]) = b;
    uint4 o;
    o.x = pack2(a.x, a.y); o.y = pack2(a.z, a.w);
    o.z = pack2(b.x, b.y); o.w = pack2(b.z, b.w);
    *(uint4*)(xb + (m0 + r) * 2048 + cc) = o;
  }
  __syncthreads();
  const int j = t & 15, dg = t >> 4;
  float a8[8] = {0.f, 0.f, 0.f, 0.f, 0.f, 0.f, 0.f, 0.f};
  const float* wp = Wgk1 + (dg * 128) * 16 + j;
  for (int dc = 0; dc < 128; dc += 4) {
    float w0 = wp[(dc + 0) * 16], w1 = wp[(dc + 1) * 16];
    float w2 = wp[(dc + 2) * 16], w3 = wp[(dc + 3) * 16];
    const int dd = dg * 128 + dc;
#pragma unroll
    for (int r = 0; r < 8; ++r) {
      float4 xv = *(const float4*)(&sx[r][dd]);
      a8[r] += xv.x * w0 + xv.y * w1 + xv.z * w2 + xv.w * w3;
    }
  }
#pragma unroll
  for (int r = 0; r < 8; ++r) red[dg][r][j] = a8[r];
  __syncthreads();
  if (t < 128) {
    int r = t >> 4, jj = t & 15;
    float s = 0.f;
#pragma unroll
    for (int g = 0; g < 16; ++g) s += red[g][r][jj];
    z1[r][jj] = s;
  }
  __syncthreads();
#pragma unroll
  for (int q = 0; q < 4; ++q) {
    int n = q * 256 + t;
    float w2v[16];
#pragma unroll
    for (int l2 = 0; l2 < 16; ++l2) w2v[l2] = Wgk2[l2 * 1024 + n];
    float bb = bgk2[n];
#pragma unroll
    for (int r = 0; r < 8; ++r) {
      float a = bb;
#pragma unroll
      for (int l2 = 0; l2 < 16; ++l2) a += z1[r][l2] * w2v[l2];
      float ls = fminf(a, 0.f) - log1pf(__expf(-fabsf(a)));
      gbuf[(m0 + r) * 1024 + n] = f2bf(ls * 0.0625f);
    }
  }
}

// ---------------- Phase A: per-chunk contribution -> bf16 S^T [128dv][64k] ----------------
__global__ __launch_bounds__(256) void chunk_contrib_kernel(
    const ushort* __restrict__ qkvg, const ushort* __restrict__ gbuf,
    ushort* __restrict__ STbuf, float* __restrict__ EGtot) {
  const int blk = blockIdx.x;           // 2048 = bh*32 + c
  const int bh = blk >> 5, c = blk & 31;
  const int b = bh >> 4, h = bh & 15;
  const long row0 = (long)b * 2048 + c * 64;
  const int th = threadIdx.x;

  __shared__ float  gc[64][65];
  __shared__ ushort khT[64][72];
  __shared__ ushort vT[128][72];

  {
    const int t = th >> 2;
    const int k0 = (th & 3) * 16;
    const ushort* gp = gbuf + (row0 + t) * 1024 + h * 64 + k0;
    uint4 a = *(const uint4*)gp;
    uint4 b4 = *(const uint4*)(gp + 8);
    float f[8];
    unpack8(a, f);
#pragma unroll
    for (int j = 0; j < 8; ++j) gc[t][k0 + j] = f[j];
    unpack8(b4, f);
#pragma unroll
    for (int j = 0; j < 8; ++j) gc[t][k0 + 8 + j] = f[j];
  }
  __syncthreads();
  GC_CUMSUM(gc, th)
  if (th < 64) EGtot[(long)blk * 64 + th] = __expf(gc[63][th]);

  {
    const int s = th & 63, kq = th >> 6;
    const ushort* kp = qkvg + (row0 + s) * 6144 + 1024 + h * 64 + kq * 16;
    uint4 a = *(const uint4*)kp;
    uint4 b4 = *(const uint4*)(kp + 8);
    float f[16];
    unpack8(a, f); unpack8(b4, f + 8);
#pragma unroll
    for (int j = 0; j < 16; ++j) {
      int k = kq * 16 + j;
      khT[k][s] = f2bf(f[j] * __expf(gc[63][k] - gc[s][k]));
    }
    const ushort* vp = qkvg + (row0 + s) * 6144 + 2048 + h * 128 + kq * 32;
#pragma unroll
    for (int u = 0; u < 4; ++u) {
      uint4 vv = *(const uint4*)(vp + u * 8);
      const ushort* pv = (const ushort*)&vv;
#pragma unroll
      for (int j = 0; j < 8; ++j) vT[kq * 32 + u * 8 + j][s] = pv[j];
    }
  }
  __syncthreads();

  const int w = th >> 6, l = th & 63;
  const int lr = l & 15, kq8 = (l >> 4) * 8;
  f32x4 acc[4][2];
#pragma unroll
  for (int m = 0; m < 4; ++m)
#pragma unroll
    for (int n = 0; n < 2; ++n) acc[m][n] = (f32x4){0.f, 0.f, 0.f, 0.f};
#pragma unroll
  for (int ks = 0; ks < 64; ks += 32) {
#pragma unroll
    for (int m = 0; m < 4; ++m) {
      bf16x8 af = *(const bf16x8*)(&khT[m * 16 + lr][ks + kq8]);
#pragma unroll
      for (int n = 0; n < 2; ++n) {
        bf16x8 bv = *(const bf16x8*)(&vT[w * 32 + n * 16 + lr][ks + kq8]);
        acc[m][n] = __builtin_amdgcn_mfma_f32_16x16x32_bf16(af, bv, acc[m][n], 0, 0, 0);
      }
    }
  }
  ushort* Cc = STbuf + (long)blk * 8192;
  const int rq = (l >> 4) * 4;
#pragma unroll
  for (int m = 0; m < 4; ++m)
#pragma unroll
    for (int n = 0; n < 2; ++n) {
      int dv = w * 32 + n * 16 + lr;
      ushort tmp[4];
#pragma unroll
      for (int r = 0; r < 4; ++r) tmp[r] = f2bf(acc[m][n][r]);
      *(uint2*)(Cc + dv * 64 + m * 16 + rq) = *(uint2*)tmp;
    }
}

// ---------------- Phase B: chunk scan on bf16 S^T, f32 running state ----------------
__global__ __launch_bounds__(256) void chunk_scan_kernel(
    ushort* __restrict__ STbuf, const float* __restrict__ EGtot) {
  const int blk = blockIdx.x;      // 256 = bh*4 + qd
  const int bh = blk >> 2, qd = blk & 3;
  const int th = threadIdx.x;
  const int dv = qd * 32 + (th >> 3);
  const int k0 = (th & 7) * 8;
  ushort* base = STbuf + (long)bh * 32 * 8192 + dv * 64 + k0;
  const float* eg = EGtot + (long)bh * 32 * 64 + k0;
  float S[8];
#pragma unroll
  for (int i = 0; i < 8; ++i) S[i] = 0.f;
  uint4 cv = *(const uint4*)base;
  float4 e0 = *(const float4*)(eg);
  float4 e1 = *(const float4*)(eg + 4);
  for (int c = 0; c < 32; ++c) {
    ushort* cur = base;
    base += 8192; eg += 64;
    uint4 nv = cv; float4 n0 = e0, n1 = e1;
    if (c < 31) {
      nv = *(const uint4*)base;
      n0 = *(const float4*)(eg);
      n1 = *(const float4*)(eg + 4);
    }
    float cf[8];
    unpack8(cv, cf);
    float ee[8] = {e0.x, e0.y, e0.z, e0.w, e1.x, e1.y, e1.z, e1.w};
    ushort so[8];
#pragma unroll
    for (int i = 0; i < 8; ++i) {
      so[i] = f2bf(S[i]);
      S[i] = S[i] * ee[i] + cf[i];
    }
    *(uint4*)cur = *(uint4*)so;
    cv = nv; e0 = n0; e1 = n1;
  }
}

// ---------------- Phase C: chunk output + fused RMSNorm*swish gate ----------------
__global__ __launch_bounds__(256) void chunk_output_kernel(
    const ushort* __restrict__ qkvg, const ushort* __restrict__ gbuf,
    const ushort* __restrict__ STbuf, const float* __restrict__ norm_w,
    ushort* __restrict__ oo) {
  const int blk = blockIdx.x;
  const int bh = blk >> 5, c = blk & 31;
  const int b = bh >> 4, h = bh & 15;
  const long row0 = (long)b * 2048 + c * 64;
  const int th = threadIdx.x;

  __shared__ __align__(16) char pool[71936];
  float  (*gc)[65]  = (float(*)[65])(pool);
  ushort (*qg)[72]  = (ushort(*)[72])(pool + 16640);
  ushort (*kg)[72]  = (ushort(*)[72])(pool + 25856);
  ushort (*vT)[72]  = (ushort(*)[72])(pool + 35072);
  ushort (*STs)[72] = (ushort(*)[72])(pool + 53504);
  ushort (*P)[72]   = (ushort(*)[72])(pool);   // alias over gc (dead after exp-apply)

  const int w = th >> 6, l = th & 63;
  const int lr = l & 15, kq8 = (l >> 4) * 8;
  const int rq = (l >> 4) * 4;

  // T14: issue gate-value loads EARLY; latency hides under cumsum+QK+PV.
  ushort gvu[8][4];
#pragma unroll
  for (int n = 0; n < 8; ++n) {
    int dv = n * 16 + lr;
#pragma unroll
    for (int r = 0; r < 4; ++r)
      gvu[n][r] = qkvg[(row0 + w * 16 + rq + r) * 6144 + 4096 + h * 128 + dv];
  }

  {
    const int t = th >> 2;
    const int k0 = (th & 3) * 16;
    const ushort* gp = gbuf + (row0 + t) * 1024 + h * 64 + k0;
    uint4 a = *(const uint4*)gp;
    uint4 b4 = *(const uint4*)(gp + 8);
    float f[8];
    unpack8(a, f);
#pragma unroll
    for (int j = 0; j < 8; ++j) gc[t][k0 + j] = f[j];
    unpack8(b4, f);
#pragma unroll
    for (int j = 0; j < 8; ++j) gc[t][k0 + 8 + j] = f[j];

    const ushort* qp = qkvg + (row0 + t) * 6144 + h * 64 + k0;
    *(uint4*)(&qg[t][k0])     = *(const uint4*)qp;
    *(uint4*)(&qg[t][k0 + 8]) = *(const uint4*)(qp + 8);
    const ushort* kp = qp + 1024;
    *(uint4*)(&kg[t][k0])     = *(const uint4*)kp;
    *(uint4*)(&kg[t][k0 + 8]) = *(const uint4*)(kp + 8);
  }
  {
    const int s = th & 63, kq = th >> 6;
    const ushort* vp = qkvg + (row0 + s) * 6144 + 2048 + h * 128 + kq * 32;
#pragma unroll
    for (int u = 0; u < 4; ++u) {
      uint4 vv = *(const uint4*)(vp + u * 8);
      const ushort* pv = (const ushort*)&vv;
#pragma unroll
      for (int j = 0; j < 8; ++j) vT[kq * 32 + u * 8 + j][s] = pv[j];
    }
  }
  {
    const int row = th >> 1;
    const int col0 = (th & 1) * 32;
    const ushort* sp = STbuf + (long)blk * 8192 + row * 64 + col0;
#pragma unroll
    for (int u = 0; u < 4; ++u)
      *(uint4*)(&STs[row][col0 + u * 8]) = *(const uint4*)(sp + u * 8);
  }
  __syncthreads();
  GC_CUMSUM(gc, th)
  {
    const int t = th & 63, kb = (th >> 6) * 16;
#pragma unroll
    for (int u = 0; u < 2; ++u) {
      uint4 qv = *(const uint4*)(&qg[t][kb + u * 8]);
      uint4 kv = *(const uint4*)(&kg[t][kb + u * 8]);
      float qf[8], kf[8];
      unpack8(qv, qf); unpack8(kv, kf);
      ushort qo[8], ko[8];
#pragma unroll
      for (int j = 0; j < 8; ++j) {
        float g = gc[t][kb + u * 8 + j];
        qo[j] = f2bf(qf[j] * __expf(g) * 0.125f);
        ko[j] = f2bf(kf[j] * __expf(-g));
      }
      *(uint4*)(&qg[t][kb + u * 8]) = *(uint4*)qo;
      *(uint4*)(&kg[t][kb + u * 8]) = *(uint4*)ko;
    }
  }
  __syncthreads();

  f32x4 acc1[4];
#pragma unroll
  for (int n = 0; n < 4; ++n) acc1[n] = (f32x4){0.f, 0.f, 0.f, 0.f};
#pragma unroll
  for (int kk = 0; kk < 64; kk += 32) {
    bf16x8 af = *(const bf16x8*)(&qg[w * 16 + lr][kk + kq8]);
#pragma unroll
    for (int n = 0; n < 4; ++n) {
      bf16x8 bv = *(const bf16x8*)(&kg[n * 16 + lr][kk + kq8]);
      acc1[n] = __builtin_amdgcn_mfma_f32_16x16x32_bf16(af, bv, acc1[n], 0, 0, 0);
    }
  }
#pragma unroll
  for (int n = 0; n < 4; ++n) {
    int s = n * 16 + lr;
#pragma unroll
    for (int r = 0; r < 4; ++r) {
      int t = w * 16 + rq + r;
      P[t][s] = f2bf(s <= t ? acc1[n][r] : 0.f);
    }
  }
  __syncthreads();

  f32x4 acc2[8];
#pragma unroll
  for (int n = 0; n < 8; ++n) acc2[n] = (f32x4){0.f, 0.f, 0.f, 0.f};
#pragma unroll
  for (int ks = 0; ks < 64; ks += 32) {
    bf16x8 af = *(const bf16x8*)(&P[w * 16 + lr][ks + kq8]);
#pragma unroll
    for (int n = 0; n < 8; ++n) {
      bf16x8 bv = *(const bf16x8*)(&vT[n * 16 + lr][ks + kq8]);
      acc2[n] = __builtin_amdgcn_mfma_f32_16x16x32_bf16(af, bv, acc2[n], 0, 0, 0);
    }
  }
#pragma unroll
  for (int kk = 0; kk < 64; kk += 32) {
    bf16x8 af = *(const bf16x8*)(&qg[w * 16 + lr][kk + kq8]);
#pragma unroll
    for (int n = 0; n < 8; ++n) {
      bf16x8 bv = *(const bf16x8*)(&STs[n * 16 + lr][kk + kq8]);
      acc2[n] = __builtin_amdgcn_mfma_f32_16x16x32_bf16(af, bv, acc2[n], 0, 0, 0);
    }
  }

  float sumsq[4] = {0.f, 0.f, 0.f, 0.f};
#pragma unroll
  for (int n = 0; n < 8; ++n)
#pragma unroll
    for (int r = 0; r < 4; ++r) sumsq[r] += acc2[n][r] * acc2[n][r];
#pragma unroll
  for (int d = 1; d < 16; d <<= 1)
#pragma unroll
    for (int r = 0; r < 4; ++r) sumsq[r] += __shfl_xor(sumsq[r], d);
  float inv[4];
#pragma unroll
  for (int r = 0; r < 4; ++r) inv[r] = rsqrtf(sumsq[r] * (1.f / 128.f) + 1e-5f);

#pragma unroll
  for (int n = 0; n < 8; ++n) {
    int dv = n * 16 + lr;
    float nw = norm_w[dv];
#pragma unroll
    for (int r = 0; r < 4; ++r) {
      float g = bf2f(gvu[n][r]);
      float sw = g / (1.f + __expf(-g));
      oo[(row0 + w * 16 + rq + r) * 2048 + h * 128 + dv] =
          f2bf(acc2[n][r] * inv[r] * nw * sw);
    }
  }
}

extern "C" void kernel_launch(void* const* d_in, const int* in_sizes, int n_in,
                              void* d_out, int out_size, void* d_ws, size_t ws_size,
                              hipStream_t stream) {
  const float* x      = (const float*)d_in[0];
  const float* Wq     = (const float*)d_in[1];
  const float* Wk     = (const float*)d_in[2];
  const float* Wv     = (const float*)d_in[3];
  const float* Wg     = (const float*)d_in[4];
  const float* Wgk1   = (const float*)d_in[5];
  const float* Wgk2   = (const float*)d_in[6];
  const float* bgk2   = (const float*)d_in[7];
  const float* norm_w = (const float*)d_in[8];
  const float* Wo     = (const float*)d_in[9];
  float* out = (float*)d_out;

  char* ws = (char*)d_ws;
  ushort* WT    = (ushort*)(ws);                       // [6144][2048] bf16  25,165,824
  ushort* WoT   = (ushort*)(ws + 25165824);            // [2048][2048] bf16   8,388,608
  ushort* qkvg  = (ushort*)(ws + 33554432);            // [8192][6144] bf16 100,663,296
  ushort* gbuf  = (ushort*)(ws + 134217728);           // [8192][1024] bf16  16,777,216
  ushort* STbuf = (ushort*)(ws + 150994944);           // [2048][128][64] bf16 33,554,432
  ushort* xb    = (ushort*)(ws + 150994944);           // overlay: dead before contrib
  float*  EGtot = (float*)(ws + 184549376);            // [2048][64] f32        524,288
  ushort* oo    = (ushort*)(ws + 185073664);           // [8192][2048] bf16  33,554,432

  dim3 blk(256);
  gate_kernel<<<dim3(1024), blk, 0, stream>>>(x, Wgk1, Wgk2, bgk2, xb, gbuf);
  transpose_w5<<<dim3(128, 32), blk, 0, stream>>>(Wq, Wk, Wv, Wg, Wo, WT, WoT);

  gemm_bt8<ushort><<<dim3(768), dim3(512), 0, stream>>>(xb, WT, qkvg, 8192, 6144, 2048);

  chunk_contrib_kernel<<<dim3(2048), blk, 0, stream>>>(qkvg, gbuf, STbuf, EGtot);
  chunk_scan_kernel<<<dim3(256), blk, 0, stream>>>(STbuf, EGtot);
  chunk_output_kernel<<<dim3(2048), blk, 0, stream>>>(qkvg, gbuf, STbuf, norm_w, oo);

  gemm_bt8<float><<<dim3(256), dim3(512), 0, stream>>>(oo, WoT, out, 8192, 2048, 2048);
}